// Round 10
// baseline (61.753 us; speedup 1.0000x reference)
//
#include <hip/hip_runtime.h>

// Depthwise temporal FIR (FW=64, SAME pad low=31/high=32), weight-norm +
// positivity clamp + bias. out[t,c] = b[c] + sum_f relu(w[f,c]/||w||) x[t-31+f,c]
//
// Rounds 6-9: any per-lane live set >~100 regs gets squeezed by the allocator
// into AGPR spill movs (~2x instruction bloat) no matter the launch-bounds /
// waves_per_eu hints. Round-10 fix: 4-way tap split -> live set ~58 VGPR,
// below the 8-wave/SIMD budget (64), so there is nothing to squeeze.
// Lane layout: lane = grp*16 + ch_local; 4 lane-groups = taps 0-15/16-31/
// 32-47/48-63 of the same 16 channels. Per output: 16 FMA/lane + tree
// reduction (shfl_xor 16, 32). Circular window xbuf[16], period-16 runtime
// loop (KTILE=128, 8 periods), 8-deep double-buffered prefetch pfA/pfB.

#define T_DIM 4096
#define C_DIM 4096
#define PAD_L 31
#define QT    16      // taps per lane (quarter filter)
#define KTILE 128     // outputs per channel-tile
#define NPER  (KTILE / 16)

template <bool GUARD>
__device__ __forceinline__ void fir_body(const float* __restrict__ x,
                                         const float* __restrict__ w,
                                         const float* __restrict__ b,
                                         float* __restrict__ out,
                                         int c, int grp, int t0) {
    const float* __restrict__ xp = x + c;                    // column base
    const float* __restrict__ wp = w + grp * QT * C_DIM + c;

    // ---- weight-norm: per-group sum of squares, tree-combined ----
    float wf[QT];
    float ss = 0.0f;
#pragma unroll
    for (int j = 0; j < QT; ++j) {
        wf[j] = wp[j * C_DIM];
        ss = fmaf(wf[j], wf[j], ss);
    }
    ss += __shfl_xor(ss, 16);
    ss += __shfl_xor(ss, 32);                                // full 64-tap norm
    const float inv = 1.0f / fmaxf(sqrtf(ss), 1e-8f);
#pragma unroll
    for (int j = 0; j < QT; ++j) wf[j] = fmaxf(wf[j] * inv, 0.0f);

    const float seed = (grp == 0) ? b[c] : 0.0f;             // bias added once

    // group g's window base: out[t0+k] uses x[base+k .. base+k+15]
    const int base = t0 - PAD_L + QT * grp;                  // base % 16 == 1

    // ---- warm-up: xbuf[(base+i) & 15] = x[base+i]; (base+i)&15 == (1+i)&15 ----
    float xbuf[QT];
#pragma unroll
    for (int i = 0; i < QT; ++i) {
        const int m = base + i;
        float v = 0.0f;
        if (!GUARD || ((unsigned)m < (unsigned)T_DIM)) v = xp[(long long)m * C_DIM];
        xbuf[(1 + i) & 15] = v;
    }

    // ---- prefetch: period p, step kk inserts m = base + 16p + 16 + kk ----
    float pfA[8], pfB[8];
#pragma unroll
    for (int i = 0; i < 8; ++i) {
        const int m = base + QT + i;
        float v = 0.0f;
        if (!GUARD || ((unsigned)m < (unsigned)T_DIM)) v = xp[(long long)m * C_DIM];
        pfA[i] = v;
    }
#pragma unroll
    for (int i = 0; i < 8; ++i) {
        const int m = base + QT + 8 + i;
        float v = 0.0f;
        if (!GUARD || ((unsigned)m < (unsigned)T_DIM)) v = xp[(long long)m * C_DIM];
        pfB[i] = v;
    }

    float res = 0.0f;
    // this lane stores rows t0 + grp + 4q (all 64 lanes store together)
    float* __restrict__ opl = out + ((long long)t0 + grp) * C_DIM + c;

    // one output step; kk is a compile-time constant (0..15 within the period)
#define FIR_STEP(kk, src)                                                     \
    {                                                                         \
        float a0 = seed, a1 = 0.0f;                                           \
        _Pragma("unroll")                                                     \
        for (int j = 0; j < QT; j += 2) {                                     \
            a0 = fmaf(wf[j],     xbuf[((kk) + j + 1) & 15], a0);              \
            a1 = fmaf(wf[j + 1], xbuf[((kk) + j + 2) & 15], a1);              \
        }                                                                     \
        xbuf[((kk) + 1) & 15] = src[(kk) & 7];                                \
        float p1 = a0 + a1;                                                   \
        p1 += __shfl_xor(p1, 16);                                             \
        p1 += __shfl_xor(p1, 32);         /* full sum on all 4 group lanes */ \
        res = (grp == ((kk) & 3)) ? p1 : res;  /* hoisted cmp, 1 cndmask */   \
        if (((kk) & 3) == 3)              /* 64-lane store, rows kb+kk-3+grp */\
            __builtin_nontemporal_store(res,                                  \
                opl + (long long)(kb + (kk) - 3) * C_DIM);                    \
    }

#pragma unroll 1
    for (int p = 0; p < NPER; ++p) {
        const int kb = p * 16;
        FIR_STEP(0, pfA)  FIR_STEP(1, pfA)  FIR_STEP(2, pfA)  FIR_STEP(3, pfA)
        FIR_STEP(4, pfA)  FIR_STEP(5, pfA)  FIR_STEP(6, pfA)  FIR_STEP(7, pfA)
        if (p < NPER - 1) {      // refill pfA for next period (uniform branch)
#pragma unroll
            for (int i = 0; i < 8; ++i) {
                const int m = base + kb + 32 + i;
                float v = 0.0f;
                if (!GUARD || ((unsigned)m < (unsigned)T_DIM)) v = xp[(long long)m * C_DIM];
                pfA[i] = v;
            }
        }
        FIR_STEP(8, pfB)  FIR_STEP(9, pfB)  FIR_STEP(10, pfB) FIR_STEP(11, pfB)
        FIR_STEP(12, pfB) FIR_STEP(13, pfB) FIR_STEP(14, pfB) FIR_STEP(15, pfB)
        if (p < NPER - 1) {      // refill pfB for next period
#pragma unroll
            for (int i = 0; i < 8; ++i) {
                const int m = base + kb + 40 + i;
                float v = 0.0f;
                if (!GUARD || ((unsigned)m < (unsigned)T_DIM)) v = xp[(long long)m * C_DIM];
                pfB[i] = v;
            }
        }
    }

#undef FIR_STEP
}

__global__ __launch_bounds__(256) void depthwise_fir_kernel(
    const float* __restrict__ x, const float* __restrict__ w,
    const float* __restrict__ b, float* __restrict__ out) {
    const int lane = threadIdx.x & 63;
    const int wave = threadIdx.x >> 6;
    const int grp  = lane >> 4;                  // tap group 0..3
    const int c    = blockIdx.y * 64 + wave * 16 + (lane & 15);
    const int t0   = blockIdx.x * KTILE;
    // zero-pad guard only at first/last time tile (block-uniform branch)
    if (blockIdx.x == 0 || blockIdx.x == gridDim.x - 1)
        fir_body<true>(x, w, b, out, c, grp, t0);
    else
        fir_body<false>(x, w, b, out, c, grp, t0);
}

extern "C" void kernel_launch(void* const* d_in, const int* in_sizes, int n_in,
                              void* d_out, int out_size, void* d_ws, size_t ws_size,
                              hipStream_t stream) {
    const float* x = (const float*)d_in[0];   // [T, C]
    const float* w = (const float*)d_in[1];   // [FW, C]
    const float* b = (const float*)d_in[2];   // [C]
    float* out = (float*)d_out;               // [T, C]

    dim3 grid(T_DIM / KTILE, C_DIM / 64);     // 32 x 64 = 2048 blocks = 8/CU
    dim3 block(256);
    hipLaunchKernelGGL(depthwise_fir_kernel, grid, block, 0, stream, x, w, b, out);
}

// Round 11
// 45.906 us; speedup vs baseline: 1.3452x; 1.3452x over previous
//
#include <hip/hip_runtime.h>

// Depthwise temporal FIR (FW=64, SAME pad low=31/high=32), weight-norm +
// positivity clamp + bias. out[t,c] = b[c] + sum_f relu(w[f,c]/||w||) x[t-31+f,c]
//
// Round-9 structure (lane-pair tap split, 32-slot circular window, period-32
// runtime loop, KTILE=128) unchanged. Round-11 change: GRID AXES SWAPPED.
// Rounds 2-10 all pinned at 2.1-2.9 TB/s HBM regardless of structure: with
// t-blocks fastest, concurrent blocks cover the same 512B channel stripe at
// different times -> scattered 256B chunks over the whole array. With
// c-blocks fastest, concurrent blocks tile entire 16KB rows contiguously ->
// near-sequential HBM streaming for both fetch and write.

#define T_DIM 4096
#define C_DIM 4096
#define PAD_L 31
#define HT    32      // taps per lane (half filter)
#define KTILE 128     // outputs per lane-pair (time tile)
#define NPER  (KTILE / 32)

template <bool GUARD>
__device__ __forceinline__ void fir_body(const float* __restrict__ x,
                                         const float* __restrict__ w,
                                         const float* __restrict__ b,
                                         float* __restrict__ out,
                                         int c, int half, int t0) {
    const float* __restrict__ xp = x + c;                      // column base
    const float* __restrict__ wp = w + half * HT * C_DIM + c;
    // this lane stores outputs t0 + k + half (k even): fold +half into the base
    float* __restrict__ opl = out + ((long long)t0 + half) * C_DIM + c;

    // ---- weight-norm: per-half sum of squares, combined across the pair ----
    float wf[HT];
    float ss = 0.0f;
#pragma unroll
    for (int j = 0; j < HT; ++j) {
        wf[j] = wp[j * C_DIM];
        ss = fmaf(wf[j], wf[j], ss);
    }
    ss += __shfl_xor(ss, 32);                                  // full 64-tap norm
    const float inv = 1.0f / fmaxf(sqrtf(ss), 1e-8f);
#pragma unroll
    for (int j = 0; j < HT; ++j) wf[j] = fmaxf(wf[j] * inv, 0.0f);

    const float bv = b[c];
    const float se = (half == 0) ? bv : 0.0f;  // seed of the partial this lane STORES (even k)
    const float so = (half == 0) ? 0.0f : bv;  // seed of the odd-k partial (stored by half1)

    // window base: out[t0+k] uses x[base+k .. base+k+31]; base % 32 == 1
    const int base = t0 - PAD_L + HT * half;

    // ---- warm-up: xbuf[(base+i) & 31] = x[base+i]; (base+i)&31 == (1+i)&31 ----
    float xbuf[HT];
#pragma unroll
    for (int i = 0; i < HT; ++i) {
        const int m = base + i;
        float v = 0.0f;
        if (!GUARD || ((unsigned)m < (unsigned)T_DIM)) v = xp[(long long)m * C_DIM];
        xbuf[(1 + i) & 31] = v;
    }

    // ---- prefetch buffers: values consumed during the CURRENT period ----
    // step kk of period p consumes m = base + 32 + p*32 + kk (inserted after use of oldest)
    float pfA[16], pfB[16];
#pragma unroll
    for (int i = 0; i < 16; ++i) {
        const int m = base + 32 + i;
        float v = 0.0f;
        if (!GUARD || ((unsigned)m < (unsigned)T_DIM)) v = xp[(long long)m * C_DIM];
        pfA[i] = v;
    }
#pragma unroll
    for (int i = 0; i < 16; ++i) {
        const int m = base + 48 + i;
        float v = 0.0f;
        if (!GUARD || ((unsigned)m < (unsigned)T_DIM)) v = xp[(long long)m * C_DIM];
        pfB[i] = v;
    }

    // 32-tap partial for step kk (compile-time kk -> static xbuf slots)
#define PARTIAL(kk, seed, dst)                                                \
    float dst;                                                                \
    {                                                                         \
        float a0 = (seed), a1 = 0.0f;                                         \
        _Pragma("unroll")                                                     \
        for (int j = 0; j < HT; j += 2) {                                     \
            a0 = fmaf(wf[j],     xbuf[((kk) + j + 1) & 31], a0);              \
            a1 = fmaf(wf[j + 1], xbuf[((kk) + j + 2) & 31], a1);              \
        }                                                                     \
        dst = a0 + a1;                                                        \
    }

    // two steps (even kk, kk+1), crosswise exchange, one store per lane-pair half
#define STEP_PAIR(kk)                                                         \
    {                                                                         \
        PARTIAL(kk, se, pe)                                                   \
        xbuf[((kk) + 1) & 31] = ((kk) < 16) ? pfA[(kk) & 15] : pfB[(kk) & 15];\
        PARTIAL((kk) + 1, so, po)                                             \
        xbuf[((kk) + 2) & 31] =                                               \
            (((kk) + 1) < 16) ? pfA[((kk) + 1) & 15] : pfB[((kk) + 1) & 15];  \
        const float snd = (half == 0) ? po : pe;                              \
        const float rcv = __shfl_xor(snd, 32);                                \
        const float res = ((half == 0) ? pe : po) + rcv;                      \
        __builtin_nontemporal_store(res, opl + (long long)(kb + (kk)) * C_DIM);\
    }

#pragma unroll 1
    for (int p = 0; p < NPER; ++p) {
        const int kb = p * 32;
        STEP_PAIR(0)  STEP_PAIR(2)  STEP_PAIR(4)  STEP_PAIR(6)
        STEP_PAIR(8)  STEP_PAIR(10) STEP_PAIR(12) STEP_PAIR(14)
        if (p < NPER - 1) {            // refill pfA for next period (uniform branch)
#pragma unroll
            for (int i = 0; i < 16; ++i) {
                const int m = base + 64 + kb + i;
                float v = 0.0f;
                if (!GUARD || ((unsigned)m < (unsigned)T_DIM)) v = xp[(long long)m * C_DIM];
                pfA[i] = v;
            }
        }
        STEP_PAIR(16) STEP_PAIR(18) STEP_PAIR(20) STEP_PAIR(22)
        STEP_PAIR(24) STEP_PAIR(26) STEP_PAIR(28) STEP_PAIR(30)
        if (p < NPER - 1) {            // refill pfB for next period
#pragma unroll
            for (int i = 0; i < 16; ++i) {
                const int m = base + 80 + kb + i;
                float v = 0.0f;
                if (!GUARD || ((unsigned)m < (unsigned)T_DIM)) v = xp[(long long)m * C_DIM];
                pfB[i] = v;
            }
        }
    }

#undef STEP_PAIR
#undef PARTIAL
}

__global__ __launch_bounds__(256)
__attribute__((amdgpu_waves_per_eu(3, 4)))
void depthwise_fir_kernel(const float* __restrict__ x, const float* __restrict__ w,
                          const float* __restrict__ b, float* __restrict__ out) {
    const int lane = threadIdx.x & 63;
    const int wave = threadIdx.x >> 6;
    // GRID SWAP: channel-blocks on x (fast-varying), time-blocks on y.
    // lanes 0-31 / 32-63 of a wave: same 32 channels, tap-halves 0 / 1
    const int c    = blockIdx.x * 128 + wave * 32 + (lane & 31);
    const int half = lane >> 5;
    const int t0   = blockIdx.y * KTILE;
    // zero-pad guard only at first/last time tile (block-uniform branch)
    if (blockIdx.y == 0 || blockIdx.y == gridDim.y - 1)
        fir_body<true>(x, w, b, out, c, half, t0);
    else
        fir_body<false>(x, w, b, out, c, half, t0);
}

extern "C" void kernel_launch(void* const* d_in, const int* in_sizes, int n_in,
                              void* d_out, int out_size, void* d_ws, size_t ws_size,
                              hipStream_t stream) {
    const float* x = (const float*)d_in[0];   // [T, C]
    const float* w = (const float*)d_in[1];   // [FW, C]
    const float* b = (const float*)d_in[2];   // [C]
    float* out = (float*)d_out;               // [T, C]

    dim3 grid(C_DIM / 128, T_DIM / KTILE);    // 32 x 32; c-blocks fastest
    dim3 block(256);
    hipLaunchKernelGGL(depthwise_fir_kernel, grid, block, 0, stream, x, w, b, out);
}